// Round 1
// baseline (858.647 us; speedup 1.0000x reference)
//
#include <hip/hip_runtime.h>

// ---------------------------------------------------------------------------
// GCN forward: 3x (GEMM 256x256 + sym-norm aggregation + bias + relu),
// then algebraically-collapsed layer 4:
//   pooled = (sum_u s_u * h3[u]) @ W4 + N*b4,
//   s_u = dis_u*(dis_u + sum_{v in out(u)} dis_v)
// followed by log_softmax. Output: [pooled(128), log_softmax(128)].
// ---------------------------------------------------------------------------

__global__ void count_kernel(const int* __restrict__ dst, int* __restrict__ cnt, int E) {
    int i = blockIdx.x * blockDim.x + threadIdx.x;
    if (i < E) atomicAdd(&cnt[dst[i]], 1);
}

// Single-block exclusive scan over cnt[N] -> offs, cursor copy, dis = rsqrt(deg)
__global__ void scan_kernel(const int* __restrict__ cnt, int* __restrict__ offs,
                            int* __restrict__ cursor, float* __restrict__ dis,
                            int N, int E) {
    __shared__ int sums[1024];
    int tid = threadIdx.x;
    int per = (N + 1023) >> 10;
    int s0 = tid * per;
    int s1 = min(s0 + per, N);
    int sum = 0;
    for (int i = s0; i < s1; i++) sum += cnt[i];
    sums[tid] = sum;
    __syncthreads();
    // Hillis-Steele inclusive scan
    for (int d = 1; d < 1024; d <<= 1) {
        int t = (tid >= d) ? sums[tid - d] : 0;
        __syncthreads();
        sums[tid] += t;
        __syncthreads();
    }
    int run = sums[tid] - sum;  // exclusive prefix
    for (int i = s0; i < s1; i++) {
        offs[i] = run;
        cursor[i] = run;
        // deg includes self-loop => always >= 1
        dis[i] = rsqrtf((float)(cnt[i] + 1));
        run += cnt[i];
    }
    if (tid == 0) offs[N] = E;
}

__global__ void scatter_kernel(const int* __restrict__ src, const int* __restrict__ dst,
                               const float* __restrict__ dis, int* __restrict__ cursor,
                               int* __restrict__ csr_src, float* __restrict__ csr_nrm, int E) {
    int i = blockIdx.x * blockDim.x + threadIdx.x;
    if (i < E) {
        int s = src[i], d = dst[i];
        int pos = atomicAdd(&cursor[d], 1);
        csr_src[pos] = s;
        csr_nrm[pos] = dis[s] * dis[d];
    }
}

// t[u] = sum over out-edges of dis[dst]  (for collapsed layer 4)
__global__ void outsum_kernel(const int* __restrict__ src, const int* __restrict__ dst,
                              const float* __restrict__ dis, float* __restrict__ t, int E) {
    int i = blockIdx.x * blockDim.x + threadIdx.x;
    if (i < E) atomicAdd(&t[src[i]], dis[dst[i]]);
}

// C[M,N] = A[M,256] @ W[256,N].  64x64 tile, 256 threads, 4x4 microtile.
__global__ __launch_bounds__(256) void gemm_kernel(const float* __restrict__ A,
                                                   const float* __restrict__ W,
                                                   float* __restrict__ C, int M, int N) {
    const int K = 256;
    __shared__ float As[16][65];   // +1 pad: break bank aliasing on transposed store
    __shared__ float Bs[16][64];
    int tid = threadIdx.x;
    int tx = tid & 15, ty = tid >> 4;
    int m0 = blockIdx.x * 64, n0 = blockIdx.y * 64;
    int a_row = tid >> 2;          // 0..63
    int a_kq  = (tid & 3) * 4;     // 0,4,8,12
    int b_k   = tid >> 4;          // 0..15
    int b_n   = (tid & 15) * 4;    // 0..60
    float c[4][4] = {};
    for (int kk = 0; kk < K; kk += 16) {
        float4 av;
        int gm = m0 + a_row;
        if (gm < M) av = *(const float4*)&A[(size_t)gm * K + kk + a_kq];
        else        av = make_float4(0.f, 0.f, 0.f, 0.f);
        As[a_kq + 0][a_row] = av.x;
        As[a_kq + 1][a_row] = av.y;
        As[a_kq + 2][a_row] = av.z;
        As[a_kq + 3][a_row] = av.w;
        *(float4*)&Bs[b_k][b_n] = *(const float4*)&W[(size_t)(kk + b_k) * N + n0 + b_n];
        __syncthreads();
#pragma unroll
        for (int k = 0; k < 16; k++) {
            float a[4], b[4];
#pragma unroll
            for (int i = 0; i < 4; i++) a[i] = As[k][ty * 4 + i];
#pragma unroll
            for (int j = 0; j < 4; j++) b[j] = Bs[k][tx * 4 + j];
#pragma unroll
            for (int i = 0; i < 4; i++)
#pragma unroll
                for (int j = 0; j < 4; j++) c[i][j] += a[i] * b[j];
        }
        __syncthreads();
    }
#pragma unroll
    for (int i = 0; i < 4; i++) {
        int gm = m0 + ty * 4 + i;
        if (gm < M) {
            float4 v = make_float4(c[i][0], c[i][1], c[i][2], c[i][3]);
            *(float4*)&C[(size_t)gm * N + n0 + tx * 4] = v;
        }
    }
}

// out[v] = relu( dis[v]^2 * T[v] + sum_{e: dst=v} nrm_e * T[src_e] + bias )
// one block per node, blockDim = F, edges staged through LDS in chunks of F.
template <int F, int RELU>
__global__ void agg_kernel(const float* __restrict__ T, const float* __restrict__ bias,
                           const int* __restrict__ offs, const int* __restrict__ csr_src,
                           const float* __restrict__ csr_nrm, const float* __restrict__ dis,
                           float* __restrict__ out) {
    __shared__ int   s_src[F];
    __shared__ float s_nrm[F];
    int v = blockIdx.x;
    int f = threadIdx.x;
    int beg = offs[v], end = offs[v + 1];
    float dv = dis[v];
    float acc = dv * dv * T[(size_t)v * F + f];
    for (int base = beg; base < end; base += F) {
        int nload = min(F, end - base);
        __syncthreads();
        if (f < nload) {
            s_src[f] = csr_src[base + f];
            s_nrm[f] = csr_nrm[base + f];
        }
        __syncthreads();
        for (int j = 0; j < nload; j++)
            acc += s_nrm[j] * T[(size_t)s_src[j] * F + f];
    }
    acc += bias[f];
    if (RELU) acc = fmaxf(acc, 0.f);
    out[(size_t)v * F + f] = acc;
}

// acc[f] += sum_r s_r * H[r][f],  s_r = dis_r*(dis_r + t_r)
__global__ void wpool_kernel(const float* __restrict__ H, const float* __restrict__ dis,
                             const float* __restrict__ t, float* __restrict__ acc, int N) {
    int f = threadIdx.x;  // 256
    float a = 0.f;
    for (int r = blockIdx.x; r < N; r += gridDim.x) {
        float s = dis[r] * (dis[r] + t[r]);
        a += s * H[(size_t)r * 256 + f];
    }
    atomicAdd(&acc[f], a);
}

// pooled = acc @ W4 + N*b4 ; out[0:128]=pooled, out[128:256]=log_softmax(pooled)
__global__ void final_kernel(const float* __restrict__ acc, const float* __restrict__ W4,
                             const float* __restrict__ b4, float* __restrict__ out, int N) {
    __shared__ float red[128];
    int c = threadIdx.x;  // 128
    float p = (float)N * b4[c];
    for (int k = 0; k < 256; k++) p += acc[k] * W4[k * 128 + c];
    out[c] = p;
    red[c] = p;
    __syncthreads();
    for (int s = 64; s > 0; s >>= 1) {
        if (c < s) red[c] = fmaxf(red[c], red[c + s]);
        __syncthreads();
    }
    float m = red[0];
    __syncthreads();
    red[c] = expf(p - m);
    __syncthreads();
    for (int s = 64; s > 0; s >>= 1) {
        if (c < s) red[c] += red[c + s];
        __syncthreads();
    }
    float lse = m + logf(red[0]);
    out[128 + c] = p - lse;
}

extern "C" void kernel_launch(void* const* d_in, const int* in_sizes, int n_in,
                              void* d_out, int out_size, void* d_ws, size_t ws_size,
                              hipStream_t stream) {
    const float* x  = (const float*)d_in[0];
    const int*   ei = (const int*)d_in[1];
    const float* W1 = (const float*)d_in[2];
    const float* b1 = (const float*)d_in[3];
    const float* W2 = (const float*)d_in[4];
    const float* b2 = (const float*)d_in[5];
    const float* W3 = (const float*)d_in[6];
    const float* b3 = (const float*)d_in[7];
    const float* W4 = (const float*)d_in[8];
    const float* b4 = (const float*)d_in[9];

    const int N = in_sizes[0] / 256;
    const int E = in_sizes[1] / 2;
    const int* src = ei;
    const int* dst = ei + E;

    char* p = (char*)d_ws;
    auto alloc = [&](size_t bytes) {
        char* r = p;
        p += (bytes + 255) & ~(size_t)255;
        return r;
    };
    int*   cnt     = (int*)alloc((size_t)N * 4);
    int*   offs    = (int*)alloc((size_t)(N + 1) * 4);
    int*   cursor  = (int*)alloc((size_t)N * 4);
    float* dis     = (float*)alloc((size_t)N * 4);
    float* tsum    = (float*)alloc((size_t)N * 4);
    int*   csr_src = (int*)alloc((size_t)E * 4);
    float* csr_nrm = (float*)alloc((size_t)E * 4);
    float* T       = (float*)alloc((size_t)N * 256 * 4);
    float* Abuf    = (float*)alloc((size_t)N * 256 * 4);
    float* accbuf  = (float*)alloc(256 * 4);

    // ---- graph preprocessing ----
    hipMemsetAsync(cnt, 0, (size_t)N * 4, stream);
    hipMemsetAsync(tsum, 0, (size_t)N * 4, stream);
    hipMemsetAsync(accbuf, 0, 256 * 4, stream);
    int eb = (E + 255) / 256;
    count_kernel<<<eb, 256, 0, stream>>>(dst, cnt, E);
    scan_kernel<<<1, 1024, 0, stream>>>(cnt, offs, cursor, dis, N, E);
    scatter_kernel<<<eb, 256, 0, stream>>>(src, dst, dis, cursor, csr_src, csr_nrm, E);
    outsum_kernel<<<eb, 256, 0, stream>>>(src, dst, dis, tsum, E);

    dim3 ggrid((N + 63) / 64, 4);
    // ---- layer 1..3 ----
    gemm_kernel<<<ggrid, 256, 0, stream>>>(x, W1, T, N, 256);
    agg_kernel<256, 1><<<N, 256, 0, stream>>>(T, b1, offs, csr_src, csr_nrm, dis, Abuf);
    gemm_kernel<<<ggrid, 256, 0, stream>>>(Abuf, W2, T, N, 256);
    agg_kernel<256, 1><<<N, 256, 0, stream>>>(T, b2, offs, csr_src, csr_nrm, dis, Abuf);
    gemm_kernel<<<ggrid, 256, 0, stream>>>(Abuf, W3, T, N, 256);
    agg_kernel<256, 1><<<N, 256, 0, stream>>>(T, b3, offs, csr_src, csr_nrm, dis, Abuf);

    // ---- collapsed layer 4 + pool + log_softmax ----
    wpool_kernel<<<256, 256, 0, stream>>>(Abuf, dis, tsum, accbuf, N);
    final_kernel<<<1, 128, 0, stream>>>(accbuf, W4, b4, (float*)d_out, N);
}

// Round 2
// 743.211 us; speedup vs baseline: 1.1553x; 1.1553x over previous
//
#include <hip/hip_runtime.h>

// ---------------------------------------------------------------------------
// GCN forward: 3x (GEMM 256x256 + sym-norm aggregation + bias + relu),
// then algebraically-collapsed layer 4:
//   pooled = (sum_u s_u * h3[u]) @ W4 + N*b4,
//   s_u = dis_u*(dis_u + sum_{v in out(u)} dis_v)
// followed by log_softmax. Output: [pooled(128), log_softmax(128)].
//
// R1: replaced 1-block scan_kernel (135us, 0.14% occupancy) with 3-phase
// parallel scan (blocksum -> bscan -> finalize), each full-grid parallel.
// ---------------------------------------------------------------------------

__global__ void count_kernel(const int* __restrict__ dst, int* __restrict__ cnt, int E) {
    int i = blockIdx.x * blockDim.x + threadIdx.x;
    if (i < E) atomicAdd(&cnt[dst[i]], 1);
}

// Phase A: per-block (256-wide) reduction of cnt -> bsum[blockIdx]
__global__ void blocksum_kernel(const int* __restrict__ cnt, int* __restrict__ bsum, int N) {
    __shared__ int s[256];
    int t = threadIdx.x;
    int i = blockIdx.x * 256 + t;
    s[t] = (i < N) ? cnt[i] : 0;
    __syncthreads();
    for (int d = 128; d > 0; d >>= 1) {
        if (t < d) s[t] += s[t + d];
        __syncthreads();
    }
    if (t == 0) bsum[blockIdx.x] = s[0];
}

// Phase B: single-block exclusive scan of bsum[B], B <= 256
__global__ void bscan_kernel(int* __restrict__ bsum, int B) {
    __shared__ int s[256];
    int t = threadIdx.x;
    int v = (t < B) ? bsum[t] : 0;
    s[t] = v;
    __syncthreads();
    for (int d = 1; d < 256; d <<= 1) {
        int x = (t >= d) ? s[t - d] : 0;
        __syncthreads();
        s[t] += x;
        __syncthreads();
    }
    if (t < B) bsum[t] = s[t] - v;  // exclusive
}

// Phase C: per-block local exclusive scan + block offset; emit offs/cursor/dis
__global__ void finalize_kernel(const int* __restrict__ cnt, const int* __restrict__ bsum,
                                int* __restrict__ offs, int* __restrict__ cursor,
                                float* __restrict__ dis, int N, int E) {
    __shared__ int s[256];
    int t = threadIdx.x;
    int i = blockIdx.x * 256 + t;
    int c = (i < N) ? cnt[i] : 0;
    s[t] = c;
    __syncthreads();
    for (int d = 1; d < 256; d <<= 1) {
        int x = (t >= d) ? s[t - d] : 0;
        __syncthreads();
        s[t] += x;
        __syncthreads();
    }
    if (i < N) {
        int ex = bsum[blockIdx.x] + s[t] - c;  // exclusive prefix
        offs[i] = ex;
        cursor[i] = ex;
        dis[i] = rsqrtf((float)(c + 1));  // deg includes self-loop => >= 1
    }
    if (blockIdx.x == 0 && t == 0) offs[N] = E;
}

__global__ void scatter_kernel(const int* __restrict__ src, const int* __restrict__ dst,
                               const float* __restrict__ dis, int* __restrict__ cursor,
                               int* __restrict__ csr_src, float* __restrict__ csr_nrm, int E) {
    int i = blockIdx.x * blockDim.x + threadIdx.x;
    if (i < E) {
        int s = src[i], d = dst[i];
        int pos = atomicAdd(&cursor[d], 1);
        csr_src[pos] = s;
        csr_nrm[pos] = dis[s] * dis[d];
    }
}

// t[u] = sum over out-edges of dis[dst]  (for collapsed layer 4)
__global__ void outsum_kernel(const int* __restrict__ src, const int* __restrict__ dst,
                              const float* __restrict__ dis, float* __restrict__ t, int E) {
    int i = blockIdx.x * blockDim.x + threadIdx.x;
    if (i < E) atomicAdd(&t[src[i]], dis[dst[i]]);
}

// C[M,N] = A[M,256] @ W[256,N].  64x64 tile, 256 threads, 4x4 microtile.
__global__ __launch_bounds__(256) void gemm_kernel(const float* __restrict__ A,
                                                   const float* __restrict__ W,
                                                   float* __restrict__ C, int M, int N) {
    const int K = 256;
    __shared__ float As[16][65];   // +1 pad: break bank aliasing on transposed store
    __shared__ float Bs[16][64];
    int tid = threadIdx.x;
    int tx = tid & 15, ty = tid >> 4;
    int m0 = blockIdx.x * 64, n0 = blockIdx.y * 64;
    int a_row = tid >> 2;          // 0..63
    int a_kq  = (tid & 3) * 4;     // 0,4,8,12
    int b_k   = tid >> 4;          // 0..15
    int b_n   = (tid & 15) * 4;    // 0..60
    float c[4][4] = {};
    for (int kk = 0; kk < K; kk += 16) {
        float4 av;
        int gm = m0 + a_row;
        if (gm < M) av = *(const float4*)&A[(size_t)gm * K + kk + a_kq];
        else        av = make_float4(0.f, 0.f, 0.f, 0.f);
        As[a_kq + 0][a_row] = av.x;
        As[a_kq + 1][a_row] = av.y;
        As[a_kq + 2][a_row] = av.z;
        As[a_kq + 3][a_row] = av.w;
        *(float4*)&Bs[b_k][b_n] = *(const float4*)&W[(size_t)(kk + b_k) * N + n0 + b_n];
        __syncthreads();
#pragma unroll
        for (int k = 0; k < 16; k++) {
            float a[4], b[4];
#pragma unroll
            for (int i = 0; i < 4; i++) a[i] = As[k][ty * 4 + i];
#pragma unroll
            for (int j = 0; j < 4; j++) b[j] = Bs[k][tx * 4 + j];
#pragma unroll
            for (int i = 0; i < 4; i++)
#pragma unroll
                for (int j = 0; j < 4; j++) c[i][j] += a[i] * b[j];
        }
        __syncthreads();
    }
#pragma unroll
    for (int i = 0; i < 4; i++) {
        int gm = m0 + ty * 4 + i;
        if (gm < M) {
            float4 v = make_float4(c[i][0], c[i][1], c[i][2], c[i][3]);
            *(float4*)&C[(size_t)gm * N + n0 + tx * 4] = v;
        }
    }
}

// out[v] = relu( dis[v]^2 * T[v] + sum_{e: dst=v} nrm_e * T[src_e] + bias )
// one block per node, blockDim = F, edges staged through LDS in chunks of F.
template <int F, int RELU>
__global__ void agg_kernel(const float* __restrict__ T, const float* __restrict__ bias,
                           const int* __restrict__ offs, const int* __restrict__ csr_src,
                           const float* __restrict__ csr_nrm, const float* __restrict__ dis,
                           float* __restrict__ out) {
    __shared__ int   s_src[F];
    __shared__ float s_nrm[F];
    int v = blockIdx.x;
    int f = threadIdx.x;
    int beg = offs[v], end = offs[v + 1];
    float dv = dis[v];
    float acc = dv * dv * T[(size_t)v * F + f];
    for (int base = beg; base < end; base += F) {
        int nload = min(F, end - base);
        __syncthreads();
        if (f < nload) {
            s_src[f] = csr_src[base + f];
            s_nrm[f] = csr_nrm[base + f];
        }
        __syncthreads();
        for (int j = 0; j < nload; j++)
            acc += s_nrm[j] * T[(size_t)s_src[j] * F + f];
    }
    acc += bias[f];
    if (RELU) acc = fmaxf(acc, 0.f);
    out[(size_t)v * F + f] = acc;
}

// acc[f] += sum_r s_r * H[r][f],  s_r = dis_r*(dis_r + t_r)
__global__ void wpool_kernel(const float* __restrict__ H, const float* __restrict__ dis,
                             const float* __restrict__ t, float* __restrict__ acc, int N) {
    int f = threadIdx.x;  // 256
    float a = 0.f;
    for (int r = blockIdx.x; r < N; r += gridDim.x) {
        float s = dis[r] * (dis[r] + t[r]);
        a += s * H[(size_t)r * 256 + f];
    }
    atomicAdd(&acc[f], a);
}

// pooled = acc @ W4 + N*b4 ; out[0:128]=pooled, out[128:256]=log_softmax(pooled)
__global__ void final_kernel(const float* __restrict__ acc, const float* __restrict__ W4,
                             const float* __restrict__ b4, float* __restrict__ out, int N) {
    __shared__ float red[128];
    int c = threadIdx.x;  // 128
    float p = (float)N * b4[c];
    for (int k = 0; k < 256; k++) p += acc[k] * W4[k * 128 + c];
    out[c] = p;
    red[c] = p;
    __syncthreads();
    for (int s = 64; s > 0; s >>= 1) {
        if (c < s) red[c] = fmaxf(red[c], red[c + s]);
        __syncthreads();
    }
    float m = red[0];
    __syncthreads();
    red[c] = expf(p - m);
    __syncthreads();
    for (int s = 64; s > 0; s >>= 1) {
        if (c < s) red[c] += red[c + s];
        __syncthreads();
    }
    float lse = m + logf(red[0]);
    out[128 + c] = p - lse;
}

extern "C" void kernel_launch(void* const* d_in, const int* in_sizes, int n_in,
                              void* d_out, int out_size, void* d_ws, size_t ws_size,
                              hipStream_t stream) {
    const float* x  = (const float*)d_in[0];
    const int*   ei = (const int*)d_in[1];
    const float* W1 = (const float*)d_in[2];
    const float* b1 = (const float*)d_in[3];
    const float* W2 = (const float*)d_in[4];
    const float* b2 = (const float*)d_in[5];
    const float* W3 = (const float*)d_in[6];
    const float* b3 = (const float*)d_in[7];
    const float* W4 = (const float*)d_in[8];
    const float* b4 = (const float*)d_in[9];

    const int N = in_sizes[0] / 256;
    const int E = in_sizes[1] / 2;
    const int* src = ei;
    const int* dst = ei + E;

    char* p = (char*)d_ws;
    auto alloc = [&](size_t bytes) {
        char* r = p;
        p += (bytes + 255) & ~(size_t)255;
        return r;
    };
    int*   cnt     = (int*)alloc((size_t)N * 4);
    int*   offs    = (int*)alloc((size_t)(N + 1) * 4);
    int*   cursor  = (int*)alloc((size_t)N * 4);
    float* dis     = (float*)alloc((size_t)N * 4);
    float* tsum    = (float*)alloc((size_t)N * 4);
    int*   bsum    = (int*)alloc(1024 * 4);
    int*   csr_src = (int*)alloc((size_t)E * 4);
    float* csr_nrm = (float*)alloc((size_t)E * 4);
    float* T       = (float*)alloc((size_t)N * 256 * 4);
    float* Abuf    = (float*)alloc((size_t)N * 256 * 4);
    float* accbuf  = (float*)alloc(256 * 4);

    // ---- graph preprocessing ----
    hipMemsetAsync(cnt, 0, (size_t)N * 4, stream);
    hipMemsetAsync(tsum, 0, (size_t)N * 4, stream);
    hipMemsetAsync(accbuf, 0, 256 * 4, stream);
    int eb = (E + 255) / 256;
    int nb = (N + 255) / 256;  // 196 for N=50000; bscan assumes nb <= 256
    count_kernel<<<eb, 256, 0, stream>>>(dst, cnt, E);
    blocksum_kernel<<<nb, 256, 0, stream>>>(cnt, bsum, N);
    bscan_kernel<<<1, 256, 0, stream>>>(bsum, nb);
    finalize_kernel<<<nb, 256, 0, stream>>>(cnt, bsum, offs, cursor, dis, N, E);
    scatter_kernel<<<eb, 256, 0, stream>>>(src, dst, dis, cursor, csr_src, csr_nrm, E);
    outsum_kernel<<<eb, 256, 0, stream>>>(src, dst, dis, tsum, E);

    dim3 ggrid((N + 63) / 64, 4);
    // ---- layer 1..3 ----
    gemm_kernel<<<ggrid, 256, 0, stream>>>(x, W1, T, N, 256);
    agg_kernel<256, 1><<<N, 256, 0, stream>>>(T, b1, offs, csr_src, csr_nrm, dis, Abuf);
    gemm_kernel<<<ggrid, 256, 0, stream>>>(Abuf, W2, T, N, 256);
    agg_kernel<256, 1><<<N, 256, 0, stream>>>(T, b2, offs, csr_src, csr_nrm, dis, Abuf);
    gemm_kernel<<<ggrid, 256, 0, stream>>>(Abuf, W3, T, N, 256);
    agg_kernel<256, 1><<<N, 256, 0, stream>>>(T, b3, offs, csr_src, csr_nrm, dis, Abuf);

    // ---- collapsed layer 4 + pool + log_softmax ----
    wpool_kernel<<<256, 256, 0, stream>>>(Abuf, dis, tsum, accbuf, N);
    final_kernel<<<1, 128, 0, stream>>>(accbuf, W4, b4, (float*)d_out, N);
}

// Round 3
// 441.867 us; speedup vs baseline: 1.9432x; 1.6820x over previous
//
#include <hip/hip_runtime.h>

// ---------------------------------------------------------------------------
// GCN forward, bf16-MFMA edition.
//   3x (bf16 MFMA GEMM 256x256 -> bf16 T; CSR sym-norm agg + bias + relu -> bf16)
//   collapsed layer 4: pooled = (sum_u s_u*h3[u]) @ W4 + N*b4; log_softmax.
// R1: parallel 3-phase scan (was 135us single-block).
// R2: GEMM fp32 vector (106us, MfmaUtil=0) -> bf16 MFMA 16x16x32, 128x128 tile,
//     LDS stride 72 bf16 (conflict-free b128), W pre-transposed to [n][k] bf16.
//     Activations bf16 end-to-end (halves agg gather traffic). fp32 accum.
// ---------------------------------------------------------------------------

typedef __attribute__((ext_vector_type(8))) short short8;
typedef __attribute__((ext_vector_type(4))) float float4v;

__device__ __forceinline__ unsigned short f2b(float f) {
    unsigned int u = __builtin_bit_cast(unsigned int, f);
    u += 0x7fffu + ((u >> 16) & 1u);   // round-to-nearest-even
    return (unsigned short)(u >> 16);
}
__device__ __forceinline__ float b2f(unsigned short b) {
    unsigned int u = ((unsigned int)b) << 16;
    return __builtin_bit_cast(float, u);
}

// ---------------- graph preprocessing ----------------

__global__ void count_kernel(const int* __restrict__ dst, int* __restrict__ cnt, int E) {
    int i = blockIdx.x * blockDim.x + threadIdx.x;
    if (i < E) atomicAdd(&cnt[dst[i]], 1);
}

__global__ void blocksum_kernel(const int* __restrict__ cnt, int* __restrict__ bsum, int N) {
    __shared__ int s[256];
    int t = threadIdx.x;
    int i = blockIdx.x * 256 + t;
    s[t] = (i < N) ? cnt[i] : 0;
    __syncthreads();
    for (int d = 128; d > 0; d >>= 1) {
        if (t < d) s[t] += s[t + d];
        __syncthreads();
    }
    if (t == 0) bsum[blockIdx.x] = s[0];
}

__global__ void bscan_kernel(int* __restrict__ bsum, int B) {
    __shared__ int s[256];
    int t = threadIdx.x;
    int v = (t < B) ? bsum[t] : 0;
    s[t] = v;
    __syncthreads();
    for (int d = 1; d < 256; d <<= 1) {
        int x = (t >= d) ? s[t - d] : 0;
        __syncthreads();
        s[t] += x;
        __syncthreads();
    }
    if (t < B) bsum[t] = s[t] - v;
}

__global__ void finalize_kernel(const int* __restrict__ cnt, const int* __restrict__ bsum,
                                int* __restrict__ offs, int* __restrict__ cursor,
                                float* __restrict__ dis, int N, int E) {
    __shared__ int s[256];
    int t = threadIdx.x;
    int i = blockIdx.x * 256 + t;
    int c = (i < N) ? cnt[i] : 0;
    s[t] = c;
    __syncthreads();
    for (int d = 1; d < 256; d <<= 1) {
        int x = (t >= d) ? s[t - d] : 0;
        __syncthreads();
        s[t] += x;
        __syncthreads();
    }
    if (i < N) {
        int ex = bsum[blockIdx.x] + s[t] - c;
        offs[i] = ex;
        cursor[i] = ex;
        dis[i] = rsqrtf((float)(c + 1));
    }
    if (blockIdx.x == 0 && t == 0) offs[N] = E;
}

__global__ void scatter_kernel(const int* __restrict__ src, const int* __restrict__ dst,
                               const float* __restrict__ dis, int* __restrict__ cursor,
                               int* __restrict__ csr_src, float* __restrict__ csr_nrm, int E) {
    int i = blockIdx.x * blockDim.x + threadIdx.x;
    if (i < E) {
        int s = src[i], d = dst[i];
        int pos = atomicAdd(&cursor[d], 1);
        csr_src[pos] = s;
        csr_nrm[pos] = dis[s] * dis[d];
    }
}

__global__ void outsum_kernel(const int* __restrict__ src, const int* __restrict__ dst,
                              const float* __restrict__ dis, float* __restrict__ t, int E) {
    int i = blockIdx.x * blockDim.x + threadIdx.x;
    if (i < E) atomicAdd(&t[src[i]], dis[dst[i]]);
}

// ---------------- dtype conversion ----------------

// fp32 [N*256] -> bf16
__global__ void convert_x_kernel(const float* __restrict__ x, unsigned short* __restrict__ xb,
                                 int total4) {
    int i = blockIdx.x * blockDim.x + threadIdx.x;
    if (i < total4) {
        float4 v = *(const float4*)&x[i * 4];
        ushort4 o;
        o.x = f2b(v.x); o.y = f2b(v.y); o.z = f2b(v.z); o.w = f2b(v.w);
        *(ushort4*)&xb[i * 4] = o;
    }
}

// Wt[n*256+k] = bf16(W[k*256+n]) for 3 weight matrices (blockIdx.y selects)
__global__ void convert_wt_kernel(const float* __restrict__ W1, const float* __restrict__ W2,
                                  const float* __restrict__ W3, unsigned short* __restrict__ Wt1,
                                  unsigned short* __restrict__ Wt2, unsigned short* __restrict__ Wt3) {
    const float* W = (blockIdx.y == 0) ? W1 : (blockIdx.y == 1) ? W2 : W3;
    unsigned short* Wt = (blockIdx.y == 0) ? Wt1 : (blockIdx.y == 1) ? Wt2 : Wt3;
    int n = blockIdx.x;
    int k = threadIdx.x;
    Wt[n * 256 + k] = f2b(W[k * 256 + n]);
}

// ---------------- bf16 MFMA GEMM ----------------
// C[M,256] = A[M,256] @ W[256,256], A bf16 [m][k], Wt bf16 [n][k], C bf16.
// Block: 256 thr (4 waves), tile 128(M) x 128(N), BK=64. Grid (ceil(M/128), 2).
// LDS row stride 72 bf16 = 144 B = 9*16B -> conflict-free b128 access.
__global__ __launch_bounds__(256, 2) void gemm_bf16_kernel(
        const unsigned short* __restrict__ A, const unsigned short* __restrict__ Wt,
        unsigned short* __restrict__ C, int M) {
    __shared__ unsigned short As[128 * 72];
    __shared__ unsigned short Bs[128 * 72];
    const int tid = threadIdx.x;
    const int lane = tid & 63;
    const int wave = tid >> 6;
    const int l15 = lane & 15;
    const int quad = lane >> 4;
    const int wm = wave & 1;          // wave M offset /64
    const int wn = wave >> 1;         // wave N offset /64
    const int m0 = blockIdx.x * 128;
    const int n0 = blockIdx.y * 128;

    float4v acc[4][4] = {};

    const int srow = tid >> 3;        // 0..31 within pass
    const int skof = (tid & 7) * 8;   // 0..56 bf16

    for (int kk = 0; kk < 256; kk += 64) {
        // stage A[128][64] and Wt[128][64]
#pragma unroll
        for (int p = 0; p < 4; p++) {
            int row = p * 32 + srow;
            int gm = m0 + row;
            float4 av = make_float4(0.f, 0.f, 0.f, 0.f);
            if (gm < M) av = *(const float4*)&A[(size_t)gm * 256 + kk + skof];
            *(float4*)&As[row * 72 + skof] = av;
            float4 bv = *(const float4*)&Wt[(size_t)(n0 + row) * 256 + kk + skof];
            *(float4*)&Bs[row * 72 + skof] = bv;
        }
        __syncthreads();
#pragma unroll
        for (int ks = 0; ks < 64; ks += 32) {
            short8 af[4], bf[4];
#pragma unroll
            for (int mi = 0; mi < 4; mi++)
                af[mi] = *(const short8*)&As[(wm * 64 + mi * 16 + l15) * 72 + ks + quad * 8];
#pragma unroll
            for (int nj = 0; nj < 4; nj++)
                bf[nj] = *(const short8*)&Bs[(wn * 64 + nj * 16 + l15) * 72 + ks + quad * 8];
#pragma unroll
            for (int mi = 0; mi < 4; mi++)
#pragma unroll
                for (int nj = 0; nj < 4; nj++)
                    acc[mi][nj] = __builtin_amdgcn_mfma_f32_16x16x32_bf16(
                        af[mi], bf[nj], acc[mi][nj], 0, 0, 0);
        }
        __syncthreads();
    }

    // epilogue: C row = m0+wm*64+mi*16+quad*4+r, col = n0+wn*64+nj*16+l15
#pragma unroll
    for (int mi = 0; mi < 4; mi++) {
#pragma unroll
        for (int r = 0; r < 4; r++) {
            int row = m0 + wm * 64 + mi * 16 + quad * 4 + r;
            if (row < M) {
#pragma unroll
                for (int nj = 0; nj < 4; nj++) {
                    int col = n0 + wn * 64 + nj * 16 + l15;
                    C[(size_t)row * 256 + col] = f2b(acc[mi][nj][r]);
                }
            }
        }
    }
}

// ---------------- aggregation (bf16 in/out, fp32 accum) ----------------
// out[v] = relu( dis[v]^2*T[v] + sum_e nrm_e*T[src_e] + bias ), 128 thr x 2 feats
template <int RELU>
__global__ void agg_bf16_kernel(const unsigned short* __restrict__ T,
                                const float* __restrict__ bias,
                                const int* __restrict__ offs, const int* __restrict__ csr_src,
                                const float* __restrict__ csr_nrm, const float* __restrict__ dis,
                                unsigned short* __restrict__ out) {
    __shared__ int   s_src[128];
    __shared__ float s_nrm[128];
    int v = blockIdx.x;
    int t = threadIdx.x;              // 0..127, owns feats 2t, 2t+1
    int beg = offs[v], end = offs[v + 1];
    float dv = dis[v];
    unsigned int w = *(const unsigned int*)&T[(size_t)v * 256 + 2 * t];
    float a0 = dv * dv * b2f((unsigned short)(w & 0xffff));
    float a1 = dv * dv * b2f((unsigned short)(w >> 16));
    for (int base = beg; base < end; base += 128) {
        int nload = min(128, end - base);
        __syncthreads();
        if (t < nload) {
            s_src[t] = csr_src[base + t];
            s_nrm[t] = csr_nrm[base + t];
        }
        __syncthreads();
        for (int j = 0; j < nload; j++) {
            unsigned int g = *(const unsigned int*)&T[(size_t)s_src[j] * 256 + 2 * t];
            float nm = s_nrm[j];
            a0 += nm * b2f((unsigned short)(g & 0xffff));
            a1 += nm * b2f((unsigned short)(g >> 16));
        }
    }
    a0 += bias[2 * t];
    a1 += bias[2 * t + 1];
    if (RELU) { a0 = fmaxf(a0, 0.f); a1 = fmaxf(a1, 0.f); }
    unsigned int o = (unsigned int)f2b(a0) | ((unsigned int)f2b(a1) << 16);
    *(unsigned int*)&out[(size_t)v * 256 + 2 * t] = o;
}

// acc[f] += sum_r s_r * H[r][f] (H bf16), s_r = dis_r*(dis_r + t_r)
__global__ void wpool_kernel(const unsigned short* __restrict__ H, const float* __restrict__ dis,
                             const float* __restrict__ tsum, float* __restrict__ acc, int N) {
    int t = threadIdx.x;              // 0..127
    float a0 = 0.f, a1 = 0.f;
    for (int r = blockIdx.x; r < N; r += gridDim.x) {
        float s = dis[r] * (dis[r] + tsum[r]);
        unsigned int w = *(const unsigned int*)&H[(size_t)r * 256 + 2 * t];
        a0 += s * b2f((unsigned short)(w & 0xffff));
        a1 += s * b2f((unsigned short)(w >> 16));
    }
    atomicAdd(&acc[2 * t], a0);
    atomicAdd(&acc[2 * t + 1], a1);
}

// pooled = acc @ W4 + N*b4 ; out[0:128]=pooled, out[128:256]=log_softmax(pooled)
__global__ void final_kernel(const float* __restrict__ acc, const float* __restrict__ W4,
                             const float* __restrict__ b4, float* __restrict__ out, int N) {
    __shared__ float red[128];
    int c = threadIdx.x;
    float p = (float)N * b4[c];
    for (int k = 0; k < 256; k++) p += acc[k] * W4[k * 128 + c];
    out[c] = p;
    red[c] = p;
    __syncthreads();
    for (int s = 64; s > 0; s >>= 1) {
        if (c < s) red[c] = fmaxf(red[c], red[c + s]);
        __syncthreads();
    }
    float m = red[0];
    __syncthreads();
    red[c] = expf(p - m);
    __syncthreads();
    for (int s = 64; s > 0; s >>= 1) {
        if (c < s) red[c] += red[c + s];
        __syncthreads();
    }
    float lse = m + logf(red[0]);
    out[128 + c] = p - lse;
}

extern "C" void kernel_launch(void* const* d_in, const int* in_sizes, int n_in,
                              void* d_out, int out_size, void* d_ws, size_t ws_size,
                              hipStream_t stream) {
    const float* x  = (const float*)d_in[0];
    const int*   ei = (const int*)d_in[1];
    const float* W1 = (const float*)d_in[2];
    const float* b1 = (const float*)d_in[3];
    const float* W2 = (const float*)d_in[4];
    const float* b2 = (const float*)d_in[5];
    const float* W3 = (const float*)d_in[6];
    const float* b3 = (const float*)d_in[7];
    const float* W4 = (const float*)d_in[8];
    const float* b4 = (const float*)d_in[9];

    const int N = in_sizes[0] / 256;
    const int E = in_sizes[1] / 2;
    const int* src = ei;
    const int* dst = ei + E;

    char* p = (char*)d_ws;
    auto alloc = [&](size_t bytes) {
        char* r = p;
        p += (bytes + 255) & ~(size_t)255;
        return r;
    };
    int*            cnt     = (int*)alloc((size_t)N * 4);
    int*            offs    = (int*)alloc((size_t)(N + 1) * 4);
    int*            cursor  = (int*)alloc((size_t)N * 4);
    float*          dis     = (float*)alloc((size_t)N * 4);
    float*          tsum    = (float*)alloc((size_t)N * 4);
    int*            bsum    = (int*)alloc(1024 * 4);
    int*            csr_src = (int*)alloc((size_t)E * 4);
    float*          csr_nrm = (float*)alloc((size_t)E * 4);
    unsigned short* xb      = (unsigned short*)alloc((size_t)N * 256 * 2);
    unsigned short* Wt1     = (unsigned short*)alloc(256 * 256 * 2);
    unsigned short* Wt2     = (unsigned short*)alloc(256 * 256 * 2);
    unsigned short* Wt3     = (unsigned short*)alloc(256 * 256 * 2);
    unsigned short* T       = (unsigned short*)alloc((size_t)N * 256 * 2);
    unsigned short* Abuf    = (unsigned short*)alloc((size_t)N * 256 * 2);
    float*          accbuf  = (float*)alloc(256 * 4);

    // ---- graph preprocessing ----
    hipMemsetAsync(cnt, 0, (size_t)N * 4, stream);
    hipMemsetAsync(tsum, 0, (size_t)N * 4, stream);
    hipMemsetAsync(accbuf, 0, 256 * 4, stream);
    int eb = (E + 255) / 256;
    int nb = (N + 255) / 256;  // 196; bscan assumes nb <= 256
    count_kernel<<<eb, 256, 0, stream>>>(dst, cnt, E);
    blocksum_kernel<<<nb, 256, 0, stream>>>(cnt, bsum, N);
    bscan_kernel<<<1, 256, 0, stream>>>(bsum, nb);
    finalize_kernel<<<nb, 256, 0, stream>>>(cnt, bsum, offs, cursor, dis, N, E);
    scatter_kernel<<<eb, 256, 0, stream>>>(src, dst, dis, cursor, csr_src, csr_nrm, E);
    outsum_kernel<<<eb, 256, 0, stream>>>(src, dst, dis, tsum, E);

    // ---- dtype conversion ----
    int total4 = N * 64;  // N*256/4
    convert_x_kernel<<<(total4 + 255) / 256, 256, 0, stream>>>(x, xb, total4);
    convert_wt_kernel<<<dim3(256, 3), 256, 0, stream>>>(W1, W2, W3, Wt1, Wt2, Wt3);

    // ---- layers 1..3 ----
    dim3 ggrid((N + 127) / 128, 2);
    gemm_bf16_kernel<<<ggrid, 256, 0, stream>>>(xb, Wt1, T, N);
    agg_bf16_kernel<1><<<N, 128, 0, stream>>>(T, b1, offs, csr_src, csr_nrm, dis, Abuf);
    gemm_bf16_kernel<<<ggrid, 256, 0, stream>>>(Abuf, Wt2, T, N);
    agg_bf16_kernel<1><<<N, 128, 0, stream>>>(T, b2, offs, csr_src, csr_nrm, dis, Abuf);
    gemm_bf16_kernel<<<ggrid, 256, 0, stream>>>(Abuf, Wt3, T, N);
    agg_bf16_kernel<1><<<N, 128, 0, stream>>>(T, b3, offs, csr_src, csr_nrm, dis, Abuf);

    // ---- collapsed layer 4 + pool + log_softmax ----
    wpool_kernel<<<256, 128, 0, stream>>>(Abuf, dis, tsum, accbuf, N);
    final_kernel<<<1, 128, 0, stream>>>(accbuf, W4, b4, (float*)d_out, N);
}

// Round 4
// 387.044 us; speedup vs baseline: 2.2185x; 1.1416x over previous
//
#include <hip/hip_runtime.h>

// ---------------------------------------------------------------------------
// GCN forward, bf16-MFMA edition.
//   3x (bf16 MFMA GEMM 256x256 -> bf16 T; CSR sym-norm agg + bias + relu -> bf16)
//   collapsed layer 4: pooled = (sum_u s_u*h3[u]) @ W4 + N*b4; log_softmax.
// R1: parallel 3-phase scan (was 135us single-block).
// R2: bf16 MFMA GEMM (was fp32 vector, 106us); bf16 activations end-to-end.
// R3: wpool 65us @ 4.8% occupancy / 3% HBM (latency-serialized 4B loads) ->
//     two-stage: 1024-block partial (16B/lane, 8 rows in flight) + 32-block
//     reduce. Expected <=10us combined.
// ---------------------------------------------------------------------------

typedef __attribute__((ext_vector_type(8))) short short8;
typedef __attribute__((ext_vector_type(4))) float float4v;

__device__ __forceinline__ unsigned short f2b(float f) {
    unsigned int u = __builtin_bit_cast(unsigned int, f);
    u += 0x7fffu + ((u >> 16) & 1u);   // round-to-nearest-even
    return (unsigned short)(u >> 16);
}
__device__ __forceinline__ float b2f(unsigned short b) {
    unsigned int u = ((unsigned int)b) << 16;
    return __builtin_bit_cast(float, u);
}

// ---------------- graph preprocessing ----------------

__global__ void count_kernel(const int* __restrict__ dst, int* __restrict__ cnt, int E) {
    int i = blockIdx.x * blockDim.x + threadIdx.x;
    if (i < E) atomicAdd(&cnt[dst[i]], 1);
}

__global__ void blocksum_kernel(const int* __restrict__ cnt, int* __restrict__ bsum, int N) {
    __shared__ int s[256];
    int t = threadIdx.x;
    int i = blockIdx.x * 256 + t;
    s[t] = (i < N) ? cnt[i] : 0;
    __syncthreads();
    for (int d = 128; d > 0; d >>= 1) {
        if (t < d) s[t] += s[t + d];
        __syncthreads();
    }
    if (t == 0) bsum[blockIdx.x] = s[0];
}

__global__ void bscan_kernel(int* __restrict__ bsum, int B) {
    __shared__ int s[256];
    int t = threadIdx.x;
    int v = (t < B) ? bsum[t] : 0;
    s[t] = v;
    __syncthreads();
    for (int d = 1; d < 256; d <<= 1) {
        int x = (t >= d) ? s[t - d] : 0;
        __syncthreads();
        s[t] += x;
        __syncthreads();
    }
    if (t < B) bsum[t] = s[t] - v;
}

__global__ void finalize_kernel(const int* __restrict__ cnt, const int* __restrict__ bsum,
                                int* __restrict__ offs, int* __restrict__ cursor,
                                float* __restrict__ dis, int N, int E) {
    __shared__ int s[256];
    int t = threadIdx.x;
    int i = blockIdx.x * 256 + t;
    int c = (i < N) ? cnt[i] : 0;
    s[t] = c;
    __syncthreads();
    for (int d = 1; d < 256; d <<= 1) {
        int x = (t >= d) ? s[t - d] : 0;
        __syncthreads();
        s[t] += x;
        __syncthreads();
    }
    if (i < N) {
        int ex = bsum[blockIdx.x] + s[t] - c;
        offs[i] = ex;
        cursor[i] = ex;
        dis[i] = rsqrtf((float)(c + 1));
    }
    if (blockIdx.x == 0 && t == 0) offs[N] = E;
}

__global__ void scatter_kernel(const int* __restrict__ src, const int* __restrict__ dst,
                               const float* __restrict__ dis, int* __restrict__ cursor,
                               int* __restrict__ csr_src, float* __restrict__ csr_nrm, int E) {
    int i = blockIdx.x * blockDim.x + threadIdx.x;
    if (i < E) {
        int s = src[i], d = dst[i];
        int pos = atomicAdd(&cursor[d], 1);
        csr_src[pos] = s;
        csr_nrm[pos] = dis[s] * dis[d];
    }
}

__global__ void outsum_kernel(const int* __restrict__ src, const int* __restrict__ dst,
                              const float* __restrict__ dis, float* __restrict__ t, int E) {
    int i = blockIdx.x * blockDim.x + threadIdx.x;
    if (i < E) atomicAdd(&t[src[i]], dis[dst[i]]);
}

// ---------------- dtype conversion ----------------

__global__ void convert_x_kernel(const float* __restrict__ x, unsigned short* __restrict__ xb,
                                 int total4) {
    int i = blockIdx.x * blockDim.x + threadIdx.x;
    if (i < total4) {
        float4 v = *(const float4*)&x[i * 4];
        ushort4 o;
        o.x = f2b(v.x); o.y = f2b(v.y); o.z = f2b(v.z); o.w = f2b(v.w);
        *(ushort4*)&xb[i * 4] = o;
    }
}

__global__ void convert_wt_kernel(const float* __restrict__ W1, const float* __restrict__ W2,
                                  const float* __restrict__ W3, unsigned short* __restrict__ Wt1,
                                  unsigned short* __restrict__ Wt2, unsigned short* __restrict__ Wt3) {
    const float* W = (blockIdx.y == 0) ? W1 : (blockIdx.y == 1) ? W2 : W3;
    unsigned short* Wt = (blockIdx.y == 0) ? Wt1 : (blockIdx.y == 1) ? Wt2 : Wt3;
    int n = blockIdx.x;
    int k = threadIdx.x;
    Wt[n * 256 + k] = f2b(W[k * 256 + n]);
}

// ---------------- bf16 MFMA GEMM ----------------
// C[M,256] = A[M,256] @ W[256,256], A bf16 [m][k], Wt bf16 [n][k], C bf16.
// Block: 256 thr (4 waves), tile 128(M) x 128(N), BK=64. Grid (ceil(M/128), 2).
// LDS row stride 72 bf16 = 144 B = 9*16B -> conflict-free b128 access.
__global__ __launch_bounds__(256, 2) void gemm_bf16_kernel(
        const unsigned short* __restrict__ A, const unsigned short* __restrict__ Wt,
        unsigned short* __restrict__ C, int M) {
    __shared__ unsigned short As[128 * 72];
    __shared__ unsigned short Bs[128 * 72];
    const int tid = threadIdx.x;
    const int lane = tid & 63;
    const int wave = tid >> 6;
    const int l15 = lane & 15;
    const int quad = lane >> 4;
    const int wm = wave & 1;
    const int wn = wave >> 1;
    const int m0 = blockIdx.x * 128;
    const int n0 = blockIdx.y * 128;

    float4v acc[4][4] = {};

    const int srow = tid >> 3;
    const int skof = (tid & 7) * 8;

    for (int kk = 0; kk < 256; kk += 64) {
#pragma unroll
        for (int p = 0; p < 4; p++) {
            int row = p * 32 + srow;
            int gm = m0 + row;
            float4 av = make_float4(0.f, 0.f, 0.f, 0.f);
            if (gm < M) av = *(const float4*)&A[(size_t)gm * 256 + kk + skof];
            *(float4*)&As[row * 72 + skof] = av;
            float4 bv = *(const float4*)&Wt[(size_t)(n0 + row) * 256 + kk + skof];
            *(float4*)&Bs[row * 72 + skof] = bv;
        }
        __syncthreads();
#pragma unroll
        for (int ks = 0; ks < 64; ks += 32) {
            short8 af[4], bf[4];
#pragma unroll
            for (int mi = 0; mi < 4; mi++)
                af[mi] = *(const short8*)&As[(wm * 64 + mi * 16 + l15) * 72 + ks + quad * 8];
#pragma unroll
            for (int nj = 0; nj < 4; nj++)
                bf[nj] = *(const short8*)&Bs[(wn * 64 + nj * 16 + l15) * 72 + ks + quad * 8];
#pragma unroll
            for (int mi = 0; mi < 4; mi++)
#pragma unroll
                for (int nj = 0; nj < 4; nj++)
                    acc[mi][nj] = __builtin_amdgcn_mfma_f32_16x16x32_bf16(
                        af[mi], bf[nj], acc[mi][nj], 0, 0, 0);
        }
        __syncthreads();
    }

#pragma unroll
    for (int mi = 0; mi < 4; mi++) {
#pragma unroll
        for (int r = 0; r < 4; r++) {
            int row = m0 + wm * 64 + mi * 16 + quad * 4 + r;
            if (row < M) {
#pragma unroll
                for (int nj = 0; nj < 4; nj++) {
                    int col = n0 + wn * 64 + nj * 16 + l15;
                    C[(size_t)row * 256 + col] = f2b(acc[mi][nj][r]);
                }
            }
        }
    }
}

// ---------------- aggregation (bf16 in/out, fp32 accum) ----------------
template <int RELU>
__global__ void agg_bf16_kernel(const unsigned short* __restrict__ T,
                                const float* __restrict__ bias,
                                const int* __restrict__ offs, const int* __restrict__ csr_src,
                                const float* __restrict__ csr_nrm, const float* __restrict__ dis,
                                unsigned short* __restrict__ out) {
    __shared__ int   s_src[128];
    __shared__ float s_nrm[128];
    int v = blockIdx.x;
    int t = threadIdx.x;
    int beg = offs[v], end = offs[v + 1];
    float dv = dis[v];
    unsigned int w = *(const unsigned int*)&T[(size_t)v * 256 + 2 * t];
    float a0 = dv * dv * b2f((unsigned short)(w & 0xffff));
    float a1 = dv * dv * b2f((unsigned short)(w >> 16));
    for (int base = beg; base < end; base += 128) {
        int nload = min(128, end - base);
        __syncthreads();
        if (t < nload) {
            s_src[t] = csr_src[base + t];
            s_nrm[t] = csr_nrm[base + t];
        }
        __syncthreads();
        for (int j = 0; j < nload; j++) {
            unsigned int g = *(const unsigned int*)&T[(size_t)s_src[j] * 256 + 2 * t];
            float nm = s_nrm[j];
            a0 += nm * b2f((unsigned short)(g & 0xffff));
            a1 += nm * b2f((unsigned short)(g >> 16));
        }
    }
    a0 += bias[2 * t];
    a1 += bias[2 * t + 1];
    if (RELU) { a0 = fmaxf(a0, 0.f); a1 = fmaxf(a1, 0.f); }
    unsigned int o = (unsigned int)f2b(a0) | ((unsigned int)f2b(a1) << 16);
    *(unsigned int*)&out[(size_t)v * 256 + 2 * t] = o;
}

// ---------------- weighted pool, two-stage ----------------
// Stage 1: partial[b][f] = sum over this block's rows of s_r * H[r][f]
// 256 thr: 32 lanes x ushort8 (16B) cover a row; 8 row-groups -> 8 rows/iter.
__global__ __launch_bounds__(256) void wpool_partial(
        const unsigned short* __restrict__ H, const float* __restrict__ dis,
        const float* __restrict__ tsum, float* __restrict__ partial, int N) {
    int tid = threadIdx.x;
    int f8 = (tid & 31) * 8;   // feature octet base
    int rg = tid >> 5;         // 0..7 row group
    float a[8] = {};
    for (int r = blockIdx.x * 8 + rg; r < N; r += gridDim.x * 8) {
        float s = dis[r] * (dis[r] + tsum[r]);
        short8 h = *(const short8*)&H[(size_t)r * 256 + f8];
#pragma unroll
        for (int i = 0; i < 8; i++) a[i] += s * b2f((unsigned short)h[i]);
    }
    __shared__ float red[8 * 256];
#pragma unroll
    for (int i = 0; i < 8; i++) red[rg * 256 + f8 + i] = a[i];
    __syncthreads();
    for (int s = 4; s > 0; s >>= 1) {
        if (rg < s) {
#pragma unroll
            for (int i = 0; i < 8; i++)
                red[rg * 256 + f8 + i] += red[(rg + s) * 256 + f8 + i];
        }
        __syncthreads();
    }
    partial[(size_t)blockIdx.x * 256 + tid] = red[tid];  // coalesced
}

// Stage 2: acc[f] += sum over 32 partial rows (grid = P/32 blocks)
__global__ void wpool_reduce(const float* __restrict__ partial, float* __restrict__ acc) {
    int f = threadIdx.x;  // 256
    int p0 = blockIdx.x * 32;
    float a = 0.f;
#pragma unroll
    for (int p = 0; p < 32; p++) a += partial[(size_t)(p0 + p) * 256 + f];
    atomicAdd(&acc[f], a);
}

// pooled = acc @ W4 + N*b4 ; out[0:128]=pooled, out[128:256]=log_softmax(pooled)
__global__ void final_kernel(const float* __restrict__ acc, const float* __restrict__ W4,
                             const float* __restrict__ b4, float* __restrict__ out, int N) {
    __shared__ float red[128];
    int c = threadIdx.x;
    float p = (float)N * b4[c];
    for (int k = 0; k < 256; k++) p += acc[k] * W4[k * 128 + c];
    out[c] = p;
    red[c] = p;
    __syncthreads();
    for (int s = 64; s > 0; s >>= 1) {
        if (c < s) red[c] = fmaxf(red[c], red[c + s]);
        __syncthreads();
    }
    float m = red[0];
    __syncthreads();
    red[c] = expf(p - m);
    __syncthreads();
    for (int s = 64; s > 0; s >>= 1) {
        if (c < s) red[c] += red[c + s];
        __syncthreads();
    }
    float lse = m + logf(red[0]);
    out[128 + c] = p - lse;
}

extern "C" void kernel_launch(void* const* d_in, const int* in_sizes, int n_in,
                              void* d_out, int out_size, void* d_ws, size_t ws_size,
                              hipStream_t stream) {
    const float* x  = (const float*)d_in[0];
    const int*   ei = (const int*)d_in[1];
    const float* W1 = (const float*)d_in[2];
    const float* b1 = (const float*)d_in[3];
    const float* W2 = (const float*)d_in[4];
    const float* b2 = (const float*)d_in[5];
    const float* W3 = (const float*)d_in[6];
    const float* b3 = (const float*)d_in[7];
    const float* W4 = (const float*)d_in[8];
    const float* b4 = (const float*)d_in[9];

    const int N = in_sizes[0] / 256;
    const int E = in_sizes[1] / 2;
    const int* src = ei;
    const int* dst = ei + E;

    char* p = (char*)d_ws;
    auto alloc = [&](size_t bytes) {
        char* r = p;
        p += (bytes + 255) & ~(size_t)255;
        return r;
    };
    int*            cnt     = (int*)alloc((size_t)N * 4);
    int*            offs    = (int*)alloc((size_t)(N + 1) * 4);
    int*            cursor  = (int*)alloc((size_t)N * 4);
    float*          dis     = (float*)alloc((size_t)N * 4);
    float*          tsum    = (float*)alloc((size_t)N * 4);
    int*            bsum    = (int*)alloc(1024 * 4);
    int*            csr_src = (int*)alloc((size_t)E * 4);
    float*          csr_nrm = (float*)alloc((size_t)E * 4);
    unsigned short* xb      = (unsigned short*)alloc((size_t)N * 256 * 2);
    unsigned short* Wt1     = (unsigned short*)alloc(256 * 256 * 2);
    unsigned short* Wt2     = (unsigned short*)alloc(256 * 256 * 2);
    unsigned short* Wt3     = (unsigned short*)alloc(256 * 256 * 2);
    unsigned short* T       = (unsigned short*)alloc((size_t)N * 256 * 2);
    unsigned short* Abuf    = (unsigned short*)alloc((size_t)N * 256 * 2);
    float*          partial = (float*)alloc((size_t)1024 * 256 * 4);
    float*          accbuf  = (float*)alloc(256 * 4);

    // ---- graph preprocessing ----
    hipMemsetAsync(cnt, 0, (size_t)N * 4, stream);
    hipMemsetAsync(tsum, 0, (size_t)N * 4, stream);
    hipMemsetAsync(accbuf, 0, 256 * 4, stream);
    int eb = (E + 255) / 256;
    int nb = (N + 255) / 256;  // 196; bscan assumes nb <= 256
    count_kernel<<<eb, 256, 0, stream>>>(dst, cnt, E);
    blocksum_kernel<<<nb, 256, 0, stream>>>(cnt, bsum, N);
    bscan_kernel<<<1, 256, 0, stream>>>(bsum, nb);
    finalize_kernel<<<nb, 256, 0, stream>>>(cnt, bsum, offs, cursor, dis, N, E);
    scatter_kernel<<<eb, 256, 0, stream>>>(src, dst, dis, cursor, csr_src, csr_nrm, E);
    outsum_kernel<<<eb, 256, 0, stream>>>(src, dst, dis, tsum, E);

    // ---- dtype conversion ----
    int total4 = N * 64;
    convert_x_kernel<<<(total4 + 255) / 256, 256, 0, stream>>>(x, xb, total4);
    convert_wt_kernel<<<dim3(256, 3), 256, 0, stream>>>(W1, W2, W3, Wt1, Wt2, Wt3);

    // ---- layers 1..3 ----
    dim3 ggrid((N + 127) / 128, 2);
    gemm_bf16_kernel<<<ggrid, 256, 0, stream>>>(xb, Wt1, T, N);
    agg_bf16_kernel<1><<<N, 128, 0, stream>>>(T, b1, offs, csr_src, csr_nrm, dis, Abuf);
    gemm_bf16_kernel<<<ggrid, 256, 0, stream>>>(Abuf, Wt2, T, N);
    agg_bf16_kernel<1><<<N, 128, 0, stream>>>(T, b2, offs, csr_src, csr_nrm, dis, Abuf);
    gemm_bf16_kernel<<<ggrid, 256, 0, stream>>>(Abuf, Wt3, T, N);
    agg_bf16_kernel<1><<<N, 128, 0, stream>>>(T, b3, offs, csr_src, csr_nrm, dis, Abuf);

    // ---- collapsed layer 4 + pool + log_softmax ----
    wpool_partial<<<1024, 256, 0, stream>>>(Abuf, dis, tsum, partial, N);
    wpool_reduce<<<32, 256, 0, stream>>>(partial, accbuf);
    final_kernel<<<1, 128, 0, stream>>>(accbuf, W4, b4, (float*)d_out, N);
}